// Round 7
// baseline (249.030 us; speedup 1.0000x reference)
//
#include <hip/hip_runtime.h>

#define FFT_N    4096
#define THREADS  512
#define ROWS_PER 4

__device__ __forceinline__ float2 cmul(float2 w, float2 v) {
    return make_float2(fmaf(w.x, v.x, -w.y * v.y), fmaf(w.x, v.y, w.y * v.x));
}
__device__ __forceinline__ float2 cmni(float2 v) { return make_float2(v.y, -v.x); }
__device__ __forceinline__ void bfly(float2& a, float2& b, float2 w) {
    float2 t = cmul(w, b);
    b = make_float2(a.x - t.x, a.y - t.y);
    a = make_float2(a.x + t.x, a.y + t.y);
}
// XOR-fold swizzle (verified round 2).
__device__ __forceinline__ int swz(int i) { return i ^ ((i >> 4) & 15) ^ ((i >> 8) & 15); }

// lgkmcnt-only barrier: global loads/stores stay in flight across it.
__device__ __forceinline__ void bar() {
    asm volatile("s_waitcnt lgkmcnt(0)" ::: "memory");
    __builtin_amdgcn_s_barrier();
}
__device__ __forceinline__ void radix8(float2 u[8], float2 A, float2 B, float2 C, float2 D) {
    bfly(u[0], u[1], A); bfly(u[2], u[3], A); bfly(u[4], u[5], A); bfly(u[6], u[7], A);
    float2 Bn = cmni(B);
    bfly(u[0], u[2], B); bfly(u[1], u[3], Bn); bfly(u[4], u[6], B); bfly(u[5], u[7], Bn);
    float2 Cn = cmni(C), Dn = cmni(D);
    bfly(u[0], u[4], C); bfly(u[1], u[5], D); bfly(u[2], u[6], Cn); bfly(u[3], u[7], Dn);
}

struct Row { float2 u[8]; };

__device__ __forceinline__ void load_row(Row& r, const float* __restrict__ xr,
                                         const float* __restrict__ xi, int t) {
    const int off[8] = {0, 2048, 1024, 3072, 512, 2560, 1536, 3584};
#pragma unroll
    for (int j = 0; j < 8; ++j) r.u[j] = make_float2(xr[t + off[j]], xi[t + off[j]]);
}

// Prefetch half a row (4 complex), pinned with a memory clobber so the loads
// cannot sink to their use site (round-6 verified mechanism).
template <int J0>
__device__ __forceinline__ void issue4(Row& n, const float* __restrict__ xr,
                                       const float* __restrict__ xi, int t, bool en) {
    const int off[8] = {0, 2048, 1024, 3072, 512, 2560, 1536, 3584};
    if (en) {
#pragma unroll
        for (int j = J0; j < J0 + 4; ++j) n.u[j] = make_float2(xr[t + off[j]], xi[t + off[j]]);
    }
    asm volatile("" ::: "memory");
}

// ---- the four passes; row state lives in LDS between passes ----
__device__ __forceinline__ void passP0(Row& r, float2* lds, int t, float2 w512) {
    const float2 one = make_float2(1.f, 0.f);
    radix8(r.u, one, one, one, w512);
    const int g0 = (int)(__brev((unsigned)t) >> 23);   // rev9(t)
#pragma unroll
    for (int j = 0; j < 8; ++j) lds[swz(8 * g0 + j)] = r.u[j];
}
__device__ __forceinline__ void passP1(float2* lds, int t, float2 C1, float2 w512) {
    Row s;
    const int b1 = (t & 7) | (((t >> 4) & 1) << 6) | (((t >> 3) & 1) << 7) | ((t >> 5) << 8);
#pragma unroll
    for (int j = 0; j < 8; ++j) s.u[j] = lds[swz(b1 + 8 * j)];
    float2 B = cmul(C1, C1), A = cmul(B, B), D = cmul(C1, w512);
    radix8(s.u, A, B, C1, D);
#pragma unroll
    for (int j = 0; j < 8; ++j) lds[swz(b1 + 8 * j)] = s.u[j];
}
__device__ __forceinline__ void passP2(float2* lds, int t, float2 C2, float2 w512) {
    Row s;
    const int b2 = (t & 63) | ((t >> 6) << 9);
#pragma unroll
    for (int j = 0; j < 8; ++j) s.u[j] = lds[swz(b2 + 64 * j)];
    float2 B = cmul(C2, C2), A = cmul(B, B), D = cmul(C2, w512);
    radix8(s.u, A, B, C2, D);
#pragma unroll
    for (int j = 0; j < 8; ++j) lds[swz(b2 + 64 * j)] = s.u[j];
}
__device__ __forceinline__ void passP3(float2* lds, int t, float2 C3, float2 w512,
                                       float* __restrict__ yr, float* __restrict__ yi) {
    Row s;
#pragma unroll
    for (int j = 0; j < 8; ++j) s.u[j] = lds[swz(t + 512 * j)];
    float2 B = cmul(C3, C3), A = cmul(B, B), D = cmul(C3, w512);
    radix8(s.u, A, B, C3, D);
#pragma unroll
    for (int j = 0; j < 8; ++j) { yr[t + 512 * j] = s.u[j].x; yi[t + 512 * j] = s.u[j].y; }
}

__global__ __launch_bounds__(THREADS, 4) void fft4096_skew_kernel(
    const float* __restrict__ x_re, const float* __restrict__ x_im,
    const float* __restrict__ W_re, const float* __restrict__ W_im,
    float* __restrict__ out, int batch, int rows_per)
{
    __shared__ float2 L0[FFT_N];
    __shared__ float2 L1[FFT_N];
    const int t = threadIdx.x;

    const float2 C1 = make_float2(W_re[(t & 7) << 6],  W_im[(t & 7) << 6]);
    const float2 C2 = make_float2(W_re[(t & 63) << 3], W_im[(t & 63) << 3]);
    const float2 C3 = make_float2(W_re[t],             W_im[t]);
    const float2 w512 = make_float2(0.70710678118654752f, -0.70710678118654752f);

    const int base = blockIdx.x * rows_per;
    float* out_im = out + (size_t)batch * FFT_N;
    Row X, Y;

    if (rows_per & 1) {   // generic fallback (not hit for batch=8192): 1 row at a time
        for (int i = 0; i < rows_per; ++i) {
            const int r = base + i;
            load_row(X, x_re + (size_t)r * FFT_N, x_im + (size_t)r * FFT_N, t);
            asm volatile("" ::: "memory");
            passP0(X, L0, t, w512);                                   bar();
            passP1(L0, t, C1, w512);                                  bar();
            passP2(L0, t, C2, w512);                                  bar();
            passP3(L0, t, C3, w512, out + (size_t)r * FFT_N, out_im + (size_t)r * FFT_N);
            bar();
        }
        return;
    }

    // Skewed 2-row pipeline: rows a (L0) and b (L1) offset by 2 phases.
    load_row(X, x_re + (size_t)base * FFT_N, x_im + (size_t)base * FFT_N, t);
    asm volatile("" ::: "memory");

    bool hp = false;        // prevB (a row finishing in L1) exists
    int prevB = 0;
    for (int it = 0; it < rows_per / 2; ++it) {
        const int a = base + 2 * it, b = a + 1;
        const bool more = (it + 1) < rows_per / 2;
        const int a2 = more ? (a + 2) : base;            // clamped; loads gated by `more`
        const float* bxr = x_re + (size_t)b * FFT_N;
        const float* bxi = x_im + (size_t)b * FFT_N;
        const float* cxr = x_re + (size_t)a2 * FFT_N;
        const float* cxi = x_im + (size_t)a2 * FFT_N;

        // s0: B-prefetch lo | A.P0 -> L0 | prevB.P2 (L1)
        issue4<0>(Y, bxr, bxi, t, true);
        passP0(X, L0, t, w512);
        if (hp) passP2(L1, t, C2, w512);
        bar();

        // s1: B-prefetch hi | A.P1 (L0) | prevB.P3 (L1) + store
        issue4<4>(Y, bxr, bxi, t, true);
        if (hp) passP3(L1, t, C3, w512,
                       out + (size_t)prevB * FFT_N, out_im + (size_t)prevB * FFT_N);
        passP1(L0, t, C1, w512);
        bar();

        // s2: A'-prefetch lo | B.P0 -> L1 | A.P2 (L0)
        issue4<0>(X, cxr, cxi, t, more);
        passP0(Y, L1, t, w512);
        passP2(L0, t, C2, w512);
        bar();

        // s3: A'-prefetch hi | B.P1 (L1) | A.P3 (L0) + store
        issue4<4>(X, cxr, cxi, t, more);
        passP3(L0, t, C3, w512,
               out + (size_t)a * FFT_N, out_im + (size_t)a * FFT_N);
        passP1(L1, t, C1, w512);
        bar();

        hp = true; prevB = b;
    }

    // Epilogue: drain last B (in L1).
    passP2(L1, t, C2, w512);
    bar();
    passP3(L1, t, C3, w512,
           out + (size_t)prevB * FFT_N, out_im + (size_t)prevB * FFT_N);
}

extern "C" void kernel_launch(void* const* d_in, const int* in_sizes, int n_in,
                              void* d_out, int out_size, void* d_ws, size_t ws_size,
                              hipStream_t stream) {
    const float* x_re = (const float*)d_in[0];
    const float* x_im = (const float*)d_in[1];
    const float* W_re = (const float*)d_in[2];
    const float* W_im = (const float*)d_in[3];
    // d_in[4] = bitrev (unused: bit-reversal folded into the pass-0 load pattern)
    const int batch = in_sizes[0] / FFT_N;
    float* out = (float*)d_out;

    int rows_per = ROWS_PER;
    while (rows_per > 1 && (batch % rows_per)) rows_per >>= 1;
    const int grid = batch / rows_per;
    fft4096_skew_kernel<<<grid, THREADS, 0, stream>>>(x_re, x_im, W_re, W_im, out, batch, rows_per);
}